// Round 7
// baseline (453.033 us; speedup 1.0000x reference)
//
#include <hip/hip_runtime.h>

typedef __attribute__((ext_vector_type(8))) short bf16x8;
typedef __attribute__((ext_vector_type(4))) float f32x4;

#define MFMA(a,b,c) __builtin_amdgcn_mfma_f32_16x16x32_bf16(a,b,c,0,0,0)

static __device__ __forceinline__ unsigned short f2bf(float f){
  unsigned u = __float_as_uint(f);
  u += 0x7FFF + ((u>>16)&1);
  return (unsigned short)(u>>16);
}
static __device__ __forceinline__ float bf2f(unsigned short b){
  return __uint_as_float(((unsigned)b)<<16);
}

// ---------------- kernel 0: weight swizzle into MFMA B-fragment order, bf16 hi/lo ----
// layout per net (ushort units): L1H(524288) L1L L2H L2L L3H(131072) L3L ; net stride 2359296
__global__ __launch_bounds__(256) void wswz(
    const float* __restrict__ wk1, const float* __restrict__ wk2, const float* __restrict__ wk3,
    const float* __restrict__ wq1, const float* __restrict__ wq2, const float* __restrict__ wq3,
    unsigned short* __restrict__ wb)
{
  int y = blockIdx.y;            // net*3 + layer
  int net = y / 3, layer = y % 3;
  const float* src = net ? (layer==0?wq1: layer==1?wq2:wq3)
                         : (layer==0?wk1: layer==1?wk2:wk3);
  int N  = (layer==2) ? 32 : 128;
  int NT = N / 16;
  int total = 32 * NT * 4 * 64;
  int e = blockIdx.x * 256 + threadIdx.x;
  if (e >= total) return;
  int lane = e & 63;
  int ks   = (e >> 6) & 3;
  int nt   = (e >> 8) % NT;
  int h    = (e >> 8) / NT;
  int k0 = ks*32 + 8*(lane>>4);
  int n0 = nt*16 + (lane&15);
  const float* s = src + (size_t)h*128*N + (size_t)k0*N + n0;
  unsigned short hi[8], lo[8];
  #pragma unroll
  for (int j=0;j<8;++j){
    float v = s[(size_t)j*N];
    unsigned short hh = f2bf(v);
    hi[j] = hh;
    lo[j] = f2bf(v - bf2f(hh));
  }
  size_t nb   = (size_t)net * 2359296;
  size_t loff = (layer==0) ? 0 : (layer==1) ? 1048576 : 2097152;
  size_t losz = (layer==2) ? 131072 : 524288;
  size_t eidx = ((((size_t)h*NT + nt)*4 + ks)*64 + lane)*8;
  unsigned short* dH = wb + nb + loff + eidx;
  unsigned short* dL = dH + losz;
  *(bf16x8*)dH = *(const bf16x8*)hi;
  *(bf16x8*)dL = *(const bf16x8*)lo;
}

// ---------------- kernel 1: fused per-head 3-layer MLP (silu,silu,tanh) ----------------
// EXACT config that produced the 326us result (RNE staging, no nontemporal).
// Wave w computes a 32-col slice (nt = 2w, 2w+1) of the 64-row tile for layers 1&2;
// layer 3 (32 cols): wave w does nt = w>>1 for row-tiles {2*(w&1), 2*(w&1)+1}.
// h packed so each XCD's resident blocks cover only 4 heads (weights L2-resident).
__global__ __launch_bounds__(256,3) void lift(
    const float* __restrict__ Kin, const float* __restrict__ Qin,
    const float* __restrict__ bk1, const float* __restrict__ bk2, const float* __restrict__ bk3,
    const float* __restrict__ bq1, const float* __restrict__ bq2, const float* __restrict__ bq3,
    const unsigned short* __restrict__ wb,
    unsigned short* __restrict__ qlift, unsigned short* __restrict__ klift,
    float* __restrict__ kout)
{
  __shared__ unsigned short XH[64][136];
  __shared__ unsigned short XL[64][136];
  int bid = blockIdx.x;
  int h   = (bid & 7)*4 + ((bid>>3)&3);   // XCD-packed head index
  int st  = (bid>>5) & 31;
  int bb  = (bid>>10) & 1;
  int net = bid>>11;
  size_t rowbase = (size_t)(bb*32 + h)*2048 + (size_t)st*64;
  const float* X = (net ? Qin : Kin) + rowbase*128;
  const unsigned short* wn = wb + (size_t)net*2359296;
  const float* b1 = (net ? bq1 : bk1) + h*128;
  const float* b2 = (net ? bq2 : bk2) + h*128;
  const float* b3 = (net ? bq3 : bk3) + h*32;
  unsigned short* lifto = net ? qlift : klift;

  int tid = threadIdx.x, w = tid >> 6, l = tid & 63;
  int lr = l & 15, lg = l >> 4;
  int acol0 = 8*lg;

  // stage 64 rows x 128 cols as bf16 hi/lo into LDS (block-wide)
  #pragma unroll
  for (int i=0;i<8;++i){
    int row = i*8 + (tid>>5);
    int col = (tid&31)*4;
    float4 v = *(const float4*)&X[(size_t)row*128 + col];
    float vv[4] = {v.x, v.y, v.z, v.w};
    unsigned short hh[4], ll[4];
    #pragma unroll
    for (int j=0;j<4;++j){ hh[j]=f2bf(vv[j]); ll[j]=f2bf(vv[j]-bf2f(hh[j])); }
    *(uint2*)&XH[row][col] = make_uint2((unsigned)hh[0] | ((unsigned)hh[1]<<16),
                                        (unsigned)hh[2] | ((unsigned)hh[3]<<16));
    *(uint2*)&XL[row][col] = make_uint2((unsigned)ll[0] | ((unsigned)ll[1]<<16),
                                        (unsigned)ll[2] | ((unsigned)ll[3]<<16));
  }
  __syncthreads();

  // ================= layers 1 & 2 (K=128 -> N=128, silu) =================
  for (int L=0; L<2; ++L){
    const unsigned short* wH = wn + (size_t)L*1048576;
    const unsigned short* wL = wH + 524288;
    const float* bias = L ? b2 : b1;
    f32x4 acc[2][4];
    #pragma unroll
    for (int ntl=0;ntl<2;++ntl)
      #pragma unroll
      for (int rt=0;rt<4;++rt)
        acc[ntl][rt] = (f32x4){0.f,0.f,0.f,0.f};

    #pragma unroll
    for (int ks=0;ks<4;++ks){
      bf16x8 bh[2], bl[2];
      #pragma unroll
      for (int ntl=0;ntl<2;++ntl){
        size_t eidx = ((((size_t)h*8 + (w*2+ntl))*4 + ks)*64 + l)*8;
        bh[ntl] = *(const bf16x8*)(wH + eidx);
        bl[ntl] = *(const bf16x8*)(wL + eidx);
      }
      #pragma unroll
      for (int rt=0;rt<4;++rt){
        bf16x8 ah = *(const bf16x8*)&XH[rt*16+lr][ks*32 + acol0];
        bf16x8 al = *(const bf16x8*)&XL[rt*16+lr][ks*32 + acol0];
        #pragma unroll
        for (int ntl=0;ntl<2;++ntl){
          f32x4 a = acc[ntl][rt];
          a = MFMA(ah, bh[ntl], a);
          a = MFMA(al, bh[ntl], a);
          a = MFMA(ah, bl[ntl], a);
          acc[ntl][rt] = a;
        }
      }
    }
    __syncthreads();   // all reads of previous acts complete before overwrite
    #pragma unroll
    for (int ntl=0;ntl<2;++ntl){
      int col = (w*2+ntl)*16 + lr;
      float bv = bias[col];
      #pragma unroll
      for (int rt=0;rt<4;++rt){
        #pragma unroll
        for (int i=0;i<4;++i){
          int row = rt*16 + 4*lg + i;
          float v = acc[ntl][rt][i] + bv;
          float sg = v * __builtin_amdgcn_rcpf(1.f + __expf(-v));
          unsigned short hh = f2bf(sg);
          XH[row][col] = hh;
          XL[row][col] = f2bf(sg - bf2f(hh));
        }
      }
    }
    __syncthreads();
  }

  // ================= layer 3 (K=128 -> N=32, tanh) + store =================
  {
    const unsigned short* wH = wn + 2097152;
    const unsigned short* wL = wH + 131072;
    int nt = w >> 1;
    int rb = (w & 1) * 2;
    f32x4 acc3[2];
    acc3[0] = (f32x4){0.f,0.f,0.f,0.f};
    acc3[1] = (f32x4){0.f,0.f,0.f,0.f};
    #pragma unroll
    for (int ks=0;ks<4;++ks){
      size_t eidx = ((((size_t)h*2 + nt)*4 + ks)*64 + l)*8;
      bf16x8 bh = *(const bf16x8*)(wH + eidx);
      bf16x8 bl = *(const bf16x8*)(wL + eidx);
      #pragma unroll
      for (int j=0;j<2;++j){
        bf16x8 ah = *(const bf16x8*)&XH[(rb+j)*16+lr][ks*32 + acol0];
        bf16x8 al = *(const bf16x8*)&XL[(rb+j)*16+lr][ks*32 + acol0];
        f32x4 a = acc3[j];
        a = MFMA(ah, bh, a);
        a = MFMA(al, bh, a);
        a = MFMA(ah, bl, a);
        acc3[j] = a;
      }
    }
    int col = nt*16 + lr;
    float bv = b3[col];
    #pragma unroll
    for (int j=0;j<2;++j){
      #pragma unroll
      for (int i=0;i<4;++i){
        int row = (rb+j)*16 + 4*lg + i;
        float v = acc3[j][i] + bv;
        float e2 = __expf(2.f*v);
        float t  = 1.f - 2.f*__builtin_amdgcn_rcpf(e2 + 1.f);
        size_t gro = (rowbase + (size_t)row)*32 + col;
        lifto[gro] = f2bf(t);
        if (net == 0) kout[gro] = t;
      }
    }
  }
}

// ---------------- kernel 2 v2: row-slab scores ----------------
// One block = 16 consecutive t-rows x ALL 2048 s for one (b,h): a single
// CONTIGUOUS 128KB output window; consecutive blockIdx -> adjacent windows
// (fill-kernel-like streaming). Causal zeros (s-tiles past the diagonal)
// are stored in the same sweep -> no separate zero pass. K-frag working set
// per XCD ~ few hundred KB -> L2-resident; Q-frag is one broadcast load.
// Wave w handles s-tiles j = w, w+4, ... (strided for intra-block balance).
__global__ __launch_bounds__(256) void scores_v2(
    const unsigned short* __restrict__ qlift,
    const unsigned short* __restrict__ klift,
    float* __restrict__ out)
{
  int bid  = blockIdx.x;
  int slab = bid & 127;          // t-slab (fast dim -> contiguous windows)
  int bh   = bid >> 7;           // 0..63
  int T0 = slab * 16;
  int tid = threadIdx.x, w = tid >> 6, l = tid & 63;
  int lr = l & 15, lg = l >> 4;
  int acol0 = 8*lg;

  const unsigned short* qb = qlift + ((size_t)bh*2048 + T0)*32;
  bf16x8 qf = *(const bf16x8*)(qb + (size_t)lr*32 + acol0);
  const unsigned short* kb = klift + (size_t)bh*2048*32;

  int t = T0 + lr;
  float* orow = out + (size_t)bh*2048*2048 + (size_t)t*2048;

  f32x4 zv = {0.f,0.f,0.f,0.f};
  for (int j = w; j < 128; j += 4){
    int s0 = j*16 + 4*lg;
    if (j <= slab){
      bf16x8 kf = *(const bf16x8*)(kb + (size_t)(j*16+lr)*32 + acol0);
      f32x4 d = MFMA(kf, qf, zv);     // D[row]=s (4*lg+i), D[col]=t (lr)
      f32x4 p;
      bool dg = (j == slab);
      #pragma unroll
      for (int i=0;i<4;++i){
        float pv = __builtin_amdgcn_rcpf(1.f + __expf(-d[i]));
        if (dg && (s0 + i > t)) pv = 0.f;
        p[i] = pv;
      }
      *(f32x4*)&orow[s0] = p;
    } else {
      *(f32x4*)&orow[s0] = zv;
    }
  }
}

extern "C" void kernel_launch(void* const* d_in, const int* in_sizes, int n_in,
                              void* d_out, int out_size, void* d_ws, size_t ws_size,
                              hipStream_t stream) {
  const float* K   = (const float*)d_in[0];
  const float* Q   = (const float*)d_in[1];
  const float* wk1 = (const float*)d_in[2];  const float* bk1 = (const float*)d_in[3];
  const float* wk2 = (const float*)d_in[4];  const float* bk2 = (const float*)d_in[5];
  const float* wk3 = (const float*)d_in[6];  const float* bk3 = (const float*)d_in[7];
  const float* wq1 = (const float*)d_in[8];  const float* bq1 = (const float*)d_in[9];
  const float* wq2 = (const float*)d_in[10]; const float* bq2 = (const float*)d_in[11];
  const float* wq3 = (const float*)d_in[12]; const float* bq3 = (const float*)d_in[13];
  float* out = (float*)d_out;

  unsigned short* ws    = (unsigned short*)d_ws;
  unsigned short* qlift = ws;                 // 4,194,304 ushorts
  unsigned short* klift = ws + 4194304;       // 4,194,304 ushorts
  unsigned short* wbase = ws + 8388608;       // 2 nets * 2,359,296 ushorts

  hipLaunchKernelGGL(wswz, dim3(256,6), dim3(256), 0, stream,
                     wk1, wk2, wk3, wq1, wq2, wq3, wbase);
  hipLaunchKernelGGL(lift, dim3(4096), dim3(256), 0, stream,
                     K, Q, bk1, bk2, bk3, bq1, bq2, bq3,
                     wbase, qlift, klift, out + 268435456ull);
  hipLaunchKernelGGL(scores_v2, dim3(8192), dim3(256), 0, stream,
                     qlift, klift, out);
}

// Round 8
// 319.492 us; speedup vs baseline: 1.4180x; 1.4180x over previous
//
#include <hip/hip_runtime.h>

typedef __attribute__((ext_vector_type(8))) short bf16x8;
typedef __attribute__((ext_vector_type(4))) float f32x4;

#define MFMA(a,b,c) __builtin_amdgcn_mfma_f32_16x16x32_bf16(a,b,c,0,0,0)

static __device__ __forceinline__ unsigned short f2bf(float f){
  unsigned u = __float_as_uint(f);
  u += 0x7FFF + ((u>>16)&1);
  return (unsigned short)(u>>16);
}
static __device__ __forceinline__ float bf2f(unsigned short b){
  return __uint_as_float(((unsigned)b)<<16);
}

// ---------------- kernel 0: weight swizzle into MFMA B-fragment order, bf16 hi/lo ----
// layout per net (ushort units): L1H(524288) L1L L2H L2L L3H(131072) L3L ; net stride 2359296
__global__ __launch_bounds__(256) void wswz(
    const float* __restrict__ wk1, const float* __restrict__ wk2, const float* __restrict__ wk3,
    const float* __restrict__ wq1, const float* __restrict__ wq2, const float* __restrict__ wq3,
    unsigned short* __restrict__ wb)
{
  int y = blockIdx.y;            // net*3 + layer
  int net = y / 3, layer = y % 3;
  const float* src = net ? (layer==0?wq1: layer==1?wq2:wq3)
                         : (layer==0?wk1: layer==1?wk2:wk3);
  int N  = (layer==2) ? 32 : 128;
  int NT = N / 16;
  int total = 32 * NT * 4 * 64;
  int e = blockIdx.x * 256 + threadIdx.x;
  if (e >= total) return;
  int lane = e & 63;
  int ks   = (e >> 6) & 3;
  int nt   = (e >> 8) % NT;
  int h    = (e >> 8) / NT;
  int k0 = ks*32 + 8*(lane>>4);
  int n0 = nt*16 + (lane&15);
  const float* s = src + (size_t)h*128*N + (size_t)k0*N + n0;
  unsigned short hi[8], lo[8];
  #pragma unroll
  for (int j=0;j<8;++j){
    float v = s[(size_t)j*N];
    unsigned short hh = f2bf(v);
    hi[j] = hh;
    lo[j] = f2bf(v - bf2f(hh));
  }
  size_t nb   = (size_t)net * 2359296;
  size_t loff = (layer==0) ? 0 : (layer==1) ? 1048576 : 2097152;
  size_t losz = (layer==2) ? 131072 : 524288;
  size_t eidx = ((((size_t)h*NT + nt)*4 + ks)*64 + lane)*8;
  unsigned short* dH = wb + nb + loff + eidx;
  unsigned short* dL = dH + losz;
  *(bf16x8*)dH = *(const bf16x8*)hi;
  *(bf16x8*)dL = *(const bf16x8*)lo;
}

// ---------------- kernel 1: fused per-head 3-layer MLP (silu,silu,tanh) ----------------
// 326us-config base. ONLY change this round: hi/lo packing uses TRUNCATION split
// (hi = bits&0xFFFF0000; lo = v - hi, exact by Sterbenz; pair is 2^-16-accurate)
// in staging + layer-1/2 activation repack: ~4 VALU ops/value vs ~12 for 2x RNE.
// Final lifto store keeps RNE f2bf (feeds scores). NO nontemporal anywhere
// (R5 showed nt hints on the big streams regress ~40us).
__global__ __launch_bounds__(256,3) void lift(
    const float* __restrict__ Kin, const float* __restrict__ Qin,
    const float* __restrict__ bk1, const float* __restrict__ bk2, const float* __restrict__ bk3,
    const float* __restrict__ bq1, const float* __restrict__ bq2, const float* __restrict__ bq3,
    const unsigned short* __restrict__ wb,
    unsigned short* __restrict__ qlift, unsigned short* __restrict__ klift,
    float* __restrict__ kout)
{
  __shared__ unsigned short XH[64][136];
  __shared__ unsigned short XL[64][136];
  int bid = blockIdx.x;
  int h   = (bid & 7)*4 + ((bid>>3)&3);   // XCD-packed head index
  int st  = (bid>>5) & 31;
  int bb  = (bid>>10) & 1;
  int net = bid>>11;
  size_t rowbase = (size_t)(bb*32 + h)*2048 + (size_t)st*64;
  const float* X = (net ? Qin : Kin) + rowbase*128;
  const unsigned short* wn = wb + (size_t)net*2359296;
  const float* b1 = (net ? bq1 : bk1) + h*128;
  const float* b2 = (net ? bq2 : bk2) + h*128;
  const float* b3 = (net ? bq3 : bk3) + h*32;
  unsigned short* lifto = net ? qlift : klift;

  int tid = threadIdx.x, w = tid >> 6, l = tid & 63;
  int lr = l & 15, lg = l >> 4;
  int acol0 = 8*lg;

  // stage 64 rows x 128 cols as trunc-split hi/lo into LDS (block-wide)
  #pragma unroll
  for (int i=0;i<8;++i){
    int row = i*8 + (tid>>5);
    int col = (tid&31)*4;
    float4 v = *(const float4*)&X[(size_t)row*128 + col];
    unsigned u0=__float_as_uint(v.x), u1=__float_as_uint(v.y),
             u2=__float_as_uint(v.z), u3=__float_as_uint(v.w);
    float l0 = v.x - __uint_as_float(u0 & 0xFFFF0000u);
    float l1 = v.y - __uint_as_float(u1 & 0xFFFF0000u);
    float l2 = v.z - __uint_as_float(u2 & 0xFFFF0000u);
    float l3 = v.w - __uint_as_float(u3 & 0xFFFF0000u);
    *(uint2*)&XH[row][col] = make_uint2((u0>>16) | (u1 & 0xFFFF0000u),
                                        (u2>>16) | (u3 & 0xFFFF0000u));
    *(uint2*)&XL[row][col] = make_uint2((__float_as_uint(l0)>>16) | (__float_as_uint(l1) & 0xFFFF0000u),
                                        (__float_as_uint(l2)>>16) | (__float_as_uint(l3) & 0xFFFF0000u));
  }
  __syncthreads();

  // ================= layers 1 & 2 (K=128 -> N=128, silu) =================
  for (int L=0; L<2; ++L){
    const unsigned short* wH = wn + (size_t)L*1048576;
    const unsigned short* wL = wH + 524288;
    const float* bias = L ? b2 : b1;
    f32x4 acc[2][4];
    #pragma unroll
    for (int ntl=0;ntl<2;++ntl)
      #pragma unroll
      for (int rt=0;rt<4;++rt)
        acc[ntl][rt] = (f32x4){0.f,0.f,0.f,0.f};

    #pragma unroll
    for (int ks=0;ks<4;++ks){
      bf16x8 bh[2], bl[2];
      #pragma unroll
      for (int ntl=0;ntl<2;++ntl){
        size_t eidx = ((((size_t)h*8 + (w*2+ntl))*4 + ks)*64 + l)*8;
        bh[ntl] = *(const bf16x8*)(wH + eidx);
        bl[ntl] = *(const bf16x8*)(wL + eidx);
      }
      #pragma unroll
      for (int rt=0;rt<4;++rt){
        bf16x8 ah = *(const bf16x8*)&XH[rt*16+lr][ks*32 + acol0];
        bf16x8 al = *(const bf16x8*)&XL[rt*16+lr][ks*32 + acol0];
        #pragma unroll
        for (int ntl=0;ntl<2;++ntl){
          f32x4 a = acc[ntl][rt];
          a = MFMA(ah, bh[ntl], a);
          a = MFMA(al, bh[ntl], a);
          a = MFMA(ah, bl[ntl], a);
          acc[ntl][rt] = a;
        }
      }
    }
    __syncthreads();   // all reads of previous acts complete before overwrite
    #pragma unroll
    for (int ntl=0;ntl<2;++ntl){
      int col = (w*2+ntl)*16 + lr;
      float bv = bias[col];
      #pragma unroll
      for (int rt=0;rt<4;++rt){
        #pragma unroll
        for (int i=0;i<4;++i){
          int row = rt*16 + 4*lg + i;
          float v = acc[ntl][rt][i] + bv;
          float sg = v * __builtin_amdgcn_rcpf(1.f + __expf(-v));
          unsigned u = __float_as_uint(sg);
          XH[row][col] = (unsigned short)(u>>16);
          float lo = sg - __uint_as_float(u & 0xFFFF0000u);
          XL[row][col] = (unsigned short)(__float_as_uint(lo)>>16);
        }
      }
    }
    __syncthreads();
  }

  // ================= layer 3 (K=128 -> N=32, tanh) + store =================
  {
    const unsigned short* wH = wn + 2097152;
    const unsigned short* wL = wH + 131072;
    int nt = w >> 1;
    int rb = (w & 1) * 2;
    f32x4 acc3[2];
    acc3[0] = (f32x4){0.f,0.f,0.f,0.f};
    acc3[1] = (f32x4){0.f,0.f,0.f,0.f};
    #pragma unroll
    for (int ks=0;ks<4;++ks){
      size_t eidx = ((((size_t)h*2 + nt)*4 + ks)*64 + l)*8;
      bf16x8 bh = *(const bf16x8*)(wH + eidx);
      bf16x8 bl = *(const bf16x8*)(wL + eidx);
      #pragma unroll
      for (int j=0;j<2;++j){
        bf16x8 ah = *(const bf16x8*)&XH[(rb+j)*16+lr][ks*32 + acol0];
        bf16x8 al = *(const bf16x8*)&XL[(rb+j)*16+lr][ks*32 + acol0];
        f32x4 a = acc3[j];
        a = MFMA(ah, bh, a);
        a = MFMA(al, bh, a);
        a = MFMA(ah, bl, a);
        acc3[j] = a;
      }
    }
    int col = nt*16 + lr;
    float bv = b3[col];
    #pragma unroll
    for (int j=0;j<2;++j){
      #pragma unroll
      for (int i=0;i<4;++i){
        int row = (rb+j)*16 + 4*lg + i;
        float v = acc3[j][i] + bv;
        float e2 = __expf(2.f*v);
        float t  = 1.f - 2.f*__builtin_amdgcn_rcpf(e2 + 1.f);
        size_t gro = (rowbase + (size_t)row)*32 + col;
        lifto[gro] = f2bf(t);
        if (net == 0) kout[gro] = t;
      }
    }
  }
}

// ---------------- kernel 2: scores = sigmoid(masked(Qlift @ Klift^T)) ----------------
// EXACT R4 version (326us config; measured ~5.8TB/s write — near fill ceiling).
// SWAPPED operands: D = mfma(Kfrag, Qfrag) so D[row]=s (score col, contiguous),
// D[col]=t (score row). Each lane stores float4 of 4 consecutive output columns;
// a wave's 64 stores form 16 full 64B lines (1KB/instruction).
__global__ __launch_bounds__(256) void scores_k(
    const unsigned short* __restrict__ qlift,
    const unsigned short* __restrict__ klift,
    float* __restrict__ out)
{
  int bid = blockIdx.x;
  int tc = bid & 15, tr = (bid >> 4) & 15, bh = bid >> 8;
  size_t sbase = (size_t)bh * 2048 * 2048;
  int r0 = tr * 128, c0 = tc * 128;   // r0: t rows (Q), c0: s cols (K)
  int tid = threadIdx.x;

  if (tc > tr){ // fully masked tile: sigmoid(f32_min) == 0
    float4 z = {0.f,0.f,0.f,0.f};
    #pragma unroll
    for (int it=0; it<16; ++it){
      int idx = it*256 + tid;     // 0..4095
      int row = idx >> 5, c4 = idx & 31;
      *(float4*)&out[sbase + (size_t)(r0+row)*2048 + c0 + c4*4] = z;
    }
    return;
  }

  int w = tid >> 6, l = tid & 63;
  int lr = l & 15, lg = l >> 4;
  int acol0 = 8*lg;
  // B operand: Q fragments for t-tiles {w*32, w*32+16}
  const unsigned short* qb = qlift + ((size_t)bh*2048 + r0 + w*32)*32;
  bf16x8 q0 = *(const bf16x8*)(qb + (size_t)lr*32 + acol0);
  bf16x8 q1 = *(const bf16x8*)(qb + (size_t)(16+lr)*32 + acol0);
  bool diag = (tc == tr);
  int t0 = r0 + w*32 + lr;
  int t1 = t0 + 16;

  // A operand: K fragments for the 8 s-tiles (prefetch all)
  const unsigned short* kb = klift + ((size_t)bh*2048 + c0)*32;
  bf16x8 kf[8];
  #pragma unroll
  for (int st8=0; st8<8; ++st8)
    kf[st8] = *(const bf16x8*)(kb + (size_t)(st8*16+lr)*32 + acol0);

  #pragma unroll
  for (int st8=0; st8<8; ++st8){
    f32x4 z4 = {0.f,0.f,0.f,0.f};
    f32x4 s0 = MFMA(kf[st8], q0, z4);   // D[s][t0-range]
    f32x4 s1 = MFMA(kf[st8], q1, z4);   // D[s][t1-range]
    int scol = c0 + st8*16 + 4*lg;
    f32x4 p0, p1;
    #pragma unroll
    for (int i=0;i<4;++i){
      float v0 = s0[i];
      float pv0 = __builtin_amdgcn_rcpf(1.f + __expf(-v0));
      if (diag && (scol + i > t0)) pv0 = 0.f;
      p0[i] = pv0;
      float v1 = s1[i];
      float pv1 = __builtin_amdgcn_rcpf(1.f + __expf(-v1));
      if (diag && (scol + i > t1)) pv1 = 0.f;
      p1[i] = pv1;
    }
    *(f32x4*)&out[sbase + (size_t)t0*2048 + scol] = p0;
    *(f32x4*)&out[sbase + (size_t)t1*2048 + scol] = p1;
  }
}

extern "C" void kernel_launch(void* const* d_in, const int* in_sizes, int n_in,
                              void* d_out, int out_size, void* d_ws, size_t ws_size,
                              hipStream_t stream) {
  const float* K   = (const float*)d_in[0];
  const float* Q   = (const float*)d_in[1];
  const float* wk1 = (const float*)d_in[2];  const float* bk1 = (const float*)d_in[3];
  const float* wk2 = (const float*)d_in[4];  const float* bk2 = (const float*)d_in[5];
  const float* wk3 = (const float*)d_in[6];  const float* bk3 = (const float*)d_in[7];
  const float* wq1 = (const float*)d_in[8];  const float* bq1 = (const float*)d_in[9];
  const float* wq2 = (const float*)d_in[10]; const float* bq2 = (const float*)d_in[11];
  const float* wq3 = (const float*)d_in[12]; const float* bq3 = (const float*)d_in[13];
  float* out = (float*)d_out;

  unsigned short* ws    = (unsigned short*)d_ws;
  unsigned short* qlift = ws;                 // 4,194,304 ushorts
  unsigned short* klift = ws + 4194304;       // 4,194,304 ushorts
  unsigned short* wbase = ws + 8388608;       // 2 nets * 2,359,296 ushorts

  hipLaunchKernelGGL(wswz, dim3(256,6), dim3(256), 0, stream,
                     wk1, wk2, wk3, wq1, wq2, wq3, wbase);
  hipLaunchKernelGGL(lift, dim3(4096), dim3(256), 0, stream,
                     K, Q, bk1, bk2, bk3, bq1, bq2, bq3,
                     wbase, qlift, klift, out + 268435456ull);
  hipLaunchKernelGGL(scores_k, dim3(16384), dim3(256), 0, stream,
                     qlift, klift, out);
}